// Round 4
// baseline (69.288 us; speedup 1.0000x reference)
//
#include <hip/hip_runtime.h>

// Gather: out[b,l,:] = table[indices[b,l], :]
// indices: [4096, 200] int32, table: [1000000, 64] f32, out: [4096, 200, 64] f32

constexpr int ROWS = 4096 * 200;      // 819200 gathered rows
constexpr int DIM = 64;               // floats per row
constexpr int HALF = ROWS / 2;        // each thread handles row r and r+HALF

typedef float f32x4 __attribute__((ext_vector_type(4)));

__global__ __launch_bounds__(256)
void hhe_gather_kernel(const int* __restrict__ indices,
                       const float* __restrict__ table,
                       float* __restrict__ out) {
    const int t = blockIdx.x * blockDim.x + threadIdx.x;
    const int r0 = t >> 4;       // first row id: 16 lanes per row
    const int c = t & 15;        // float4 slot within row
    if (r0 >= HALF) return;
    const int r1 = r0 + HALF;

    // Indices are single-use: non-temporal load keeps them out of L3.
    const int idx0 = __builtin_nontemporal_load(indices + r0);
    const int idx1 = __builtin_nontemporal_load(indices + r1);

    const f32x4* __restrict__ src0 =
        reinterpret_cast<const f32x4*>(table + (long long)idx0 * DIM);
    const f32x4* __restrict__ src1 =
        reinterpret_cast<const f32x4*>(table + (long long)idx1 * DIM);

    // Two independent load chains per thread (MLP=2).
    f32x4 v0 = src0[c];
    f32x4 v1 = src1[c];

    f32x4* __restrict__ dst0 = reinterpret_cast<f32x4*>(out + (long long)r0 * DIM);
    f32x4* __restrict__ dst1 = reinterpret_cast<f32x4*>(out + (long long)r1 * DIM);

    // Non-temporal stores: the 210 MB output stream must not evict the table.
    __builtin_nontemporal_store(v0, &dst0[c]);
    __builtin_nontemporal_store(v1, &dst1[c]);
}

extern "C" void kernel_launch(void* const* d_in, const int* in_sizes, int n_in,
                              void* d_out, int out_size, void* d_ws, size_t ws_size,
                              hipStream_t stream) {
    const int*   indices = (const int*)d_in[0];
    const float* table   = (const float*)d_in[1];
    float*       out     = (float*)d_out;

    const int total_threads = HALF * 16;               // 6,553,600
    const int block = 256;
    const int grid = (total_threads + block - 1) / block;  // 25600

    hhe_gather_kernel<<<grid, block, 0, stream>>>(indices, table, out);
}

// Round 5
// 64.724 us; speedup vs baseline: 1.0705x; 1.0705x over previous
//
#include <hip/hip_runtime.h>

// Gather: out[b,l,:] = table[indices[b,l], :]
// indices: [4096, 200] int32, table: [1000000, 64] f32, out: [4096, 200, 64] f32
//
// Structure (round-3, best = 64.4 us):
//  - 16 lanes per row, one float4 (16 B) per lane: coalesced 256 B row reads.
//  - Table reads cached (repeats hit L2/L3; table ~244 MiB nearly fits L3).
//  - Output stores non-temporal: the 210 MB write stream must not evict the
//    table (this was +16% vs cached stores, round 1 -> 3).
// Floor: ~356 MB mandatory HBM traffic/replay @ ~5.5 TB/s effective for
// mixed random-256B-read + stream-write.

constexpr int ROWS = 4096 * 200;      // 819200 gathered rows
constexpr int DIM = 64;               // floats per row
constexpr int VEC_PER_ROW = DIM / 4;  // 16 float4 per row

typedef float f32x4 __attribute__((ext_vector_type(4)));

__global__ __launch_bounds__(256)
void hhe_gather_kernel(const int* __restrict__ indices,
                       const float* __restrict__ table,
                       float* __restrict__ out) {
    const int t = blockIdx.x * blockDim.x + threadIdx.x;
    const int r = t >> 4;        // row id: 16 lanes per row
    const int c = t & 15;        // float4 slot within row
    if (r >= ROWS) return;

    const long long idx = (long long)indices[r];
    const f32x4* __restrict__ src =
        reinterpret_cast<const f32x4*>(table + idx * DIM);
    f32x4* __restrict__ dst =
        reinterpret_cast<f32x4*>(out + (long long)r * DIM);

    f32x4 v = src[c];
    __builtin_nontemporal_store(v, &dst[c]);
}

extern "C" void kernel_launch(void* const* d_in, const int* in_sizes, int n_in,
                              void* d_out, int out_size, void* d_ws, size_t ws_size,
                              hipStream_t stream) {
    const int*   indices = (const int*)d_in[0];
    const float* table   = (const float*)d_in[1];
    float*       out     = (float*)d_out;

    const int total_threads = ROWS * VEC_PER_ROW;      // 13,107,200
    const int block = 256;
    const int grid = (total_threads + block - 1) / block;  // 51200

    hhe_gather_kernel<<<grid, block, 0, stream>>>(indices, table, out);
}